// Round 15
// baseline (140.584 us; speedup 1.0000x reference)
//
#include <hip/hip_runtime.h>
#include <math.h>

#define Bc 4
#define Nc 512
#define Pc 1024
#define Kc 20
#define MUL 64
#define NBc 20
#define HID 100
#define Tc 3
#define CUTc 4.0f
#define Ec (Nc * Kc)        /* 10240 */
#define PEc (Pc * Kc)       /* 20480 */
#define NA (Bc * Nc)        /* 2048 */
#define NP (Bc * Pc)        /* 4096 */
#define ET (Bc * Ec)        /* 40960 */
#define PET (Bc * PEc)      /* 81920 */
#define TBL 1024            /* w-table points over r in [0, RMAXT] */
#define RMAXT 5.25f         /* rbf(r) dead beyond ~5; absmax insensitive (r13/r14) */
#define CAP 64              /* bucket capacity per dst (max degree ~38 expected) */
#define TROWS 4
#define TBLOCKS (6 * TBL / TROWS)   /* 1536 */
#define EBLOCKS 32
#define ASCAN (NA / 4)              /* 512  */
#define PSCAN (NP / 4)              /* 1024 */
#define CH 256                      /* edge-chunk staged in LDS per scan block */

__device__ __forceinline__ float silu_f(float x) { return x / (1.0f + __expf(-x)); }
__device__ __forceinline__ float lane_bcast_f(float v, int l) {
    return __int_as_float(__builtin_amdgcn_readlane(__float_as_int(v), l));
}

// ---------------------------------------------------------------------------
// Per-node edge scan: the wave owning dst node (b, nloc) scans its batch's
// edge list (LDS-staged dst ids, ballot match), computes r for matches, and
// writes ITS OWN bucket row + count. No atomics, no pre-zeroed memory ->
// bucket building is dependency-free and fuses into the front launch.
// ---------------------------------------------------------------------------
__device__ __forceinline__ void scan_node(
    const int* __restrict__ edges,    // batch-local (Eper,2)
    const float* __restrict__ displ,  // batch-local (Eper,3)
    const float* __restrict__ srcpos, // atom positions (global)
    float px, float py, float pz,     // this dst node's position
    const float* __restrict__ C,      // cell row (9)
    int b, int nloc, int Eper, int nglob,
    int* __restrict__ sdst,           // LDS scratch [CH]
    float* __restrict__ brk, int* __restrict__ bsk, int* __restrict__ cnt)
{
    int t = threadIdx.x;
    int lane = t & 63;
    float c0v = C[0], c3 = C[3], c6 = C[6];
    float c1 = C[1], c4 = C[4], c7 = C[7];
    float c2 = C[2], c5 = C[5], c8 = C[8];
    int pos = 0;
    for (int base = 0; base < Eper; base += CH) {
        int2 e2 = ((const int2*)edges)[base + t];   // coalesced 8B; keep dst
        sdst[t] = e2.y;
        __syncthreads();
#pragma unroll
        for (int k = 0; k < CH / 64; ++k) {
            int d = sdst[k * 64 + lane];
            unsigned long long mask = __ballot(d == nloc);
            while (mask) {
                int p = __ffsll((long long)mask) - 1;
                mask &= mask - 1;
                int i = __builtin_amdgcn_readfirstlane(base + k * 64 + p);
                int sl = edges[i * 2];               // uniform
                int sg = sl + b * Nc;
                float d0 = displ[i * 3 + 0];
                float d1 = displ[i * 3 + 1];
                float d2 = displ[i * 3 + 2];
                float dx = d0 * c0v + d1 * c3 + d2 * c6;
                float dy = d0 * c1 + d1 * c4 + d2 * c7;
                float dz = d0 * c2 + d1 * c5 + d2 * c8;
                float vx = px - (srcpos[sg * 3 + 0] + dx);
                float vy = py - (srcpos[sg * 3 + 1] + dy);
                float vz = pz - (srcpos[sg * 3 + 2] + dz);
                float r = sqrtf(vx * vx + vy * vy + vz * vz);
                if (pos < CAP && lane == 0) {
                    brk[(size_t)nglob * CAP + pos] = r;
                    bsk[(size_t)nglob * CAP + pos] = sg;
                }
                ++pos;
            }
        }
        __syncthreads();
    }
    if (lane == 0) cnt[nglob] = pos;
}

// ---------------------------------------------------------------------------
// Mega-front: ALL dependency-free work in one full-width launch
// (r8/r13 lesson: never narrow the grid; r10 lesson: never grid.sync):
//   [0,1536):      w-tables as (w,dw) float2, TROWS rows/block (+1 overlap)
//   [1536,1568):   embedding row 0
//   [1568,2080):   atom-graph scan -> buckets (4 nodes/block)
//   [2080,3104):   probe-graph scan -> buckets (4 nodes/block)
// ---------------------------------------------------------------------------
__global__ __launch_bounds__(256) void megafront_kernel(
    const float* __restrict__ Wr1, const float* __restrict__ pWr1,
    const float* __restrict__ br1, const float* __restrict__ pbr1,
    const float* __restrict__ Wr2, const float* __restrict__ pWr2,
    const float* __restrict__ br2, const float* __restrict__ pbr2,
    const int* __restrict__ nodes, const float* __restrict__ Wemb,
    const float* __restrict__ apos, const float* __restrict__ ppos,
    const int* __restrict__ a_edges, const int* __restrict__ p_edges,
    const float* __restrict__ a_disp, const float* __restrict__ p_disp,
    const float* __restrict__ cell,
    float* __restrict__ h0row,
    int* __restrict__ cnt_a, float* __restrict__ br_a, int* __restrict__ bs_a,
    int* __restrict__ cnt_p, float* __restrict__ br_p, int* __restrict__ bs_p,
    float2* __restrict__ wtab)        // (6*TBL, 64) of (w, dw)
{
    __shared__ float Hs[(TROWS + 1) * HID];   // 2.0 KB
    __shared__ float Ws[(TROWS + 1) * MUL];   // 1.25 KB
    __shared__ int   sdst[CH];                // 1.0 KB
    int bid = blockIdx.x;
    int t = threadIdx.x;

    if (bid < TBLOCKS) {
        // ---------------- w-tables ----------------
        int grow0 = bid * TROWS;
        int ly = grow0 / TBL;
        int rin = grow0 % TBL;
        int t3 = (ly < 3) ? ly : ly - 3;
        const float* w1 = ((ly < 3) ? Wr1 : pWr1) + (size_t)t3 * NBc * HID;
        const float* b1 = ((ly < 3) ? br1 : pbr1) + (size_t)t3 * HID;
        const float* w2 = ((ly < 3) ? Wr2 : pWr2) + (size_t)t3 * HID * MUL;
        const float* b2 = ((ly < 3) ? br2 : pbr2) + (size_t)t3 * MUL;
        const float step = CUTc / (NBc - 1);
        const float inv_sigma = (float)NBc / CUTc;

        for (int id = t; id < (TROWS + 1) * HID; id += 256) {
            int il = id / HID, j = id - il * HID;
            float r = (float)(rin + il) * (RMAXT / (float)TBL);
            float s = b1[j];
#pragma unroll
            for (int k = 0; k < NBc; ++k) {
                float tt = (r - k * step) * inv_sigma;
                s = fmaf(__expf(-tt * tt), w1[k * HID + j], s);
            }
            Hs[id] = silu_f(s);
        }
        __syncthreads();

        for (int id = t; id < (TROWS + 1) * MUL; id += 256) {
            int il = id >> 6, c = id & 63;
            float acc = b2[c];
#pragma unroll 4
            for (int j = 0; j < HID; ++j)
                acc = fmaf(Hs[il * HID + j], w2[(size_t)j * MUL + c], acc);
            Ws[id] = acc;
        }
        __syncthreads();

        {
            int il = t >> 6, c = t & 63;
            float w0 = Ws[il * MUL + c];
            float w1v = Ws[(il + 1) * MUL + c];
            wtab[(size_t)(grow0 + il) * MUL + c] = make_float2(w0, w1v - w0);
        }
    } else if (bid < TBLOCKS + EBLOCKS) {
        // ---------------- embedding row 0 ----------------
        int idx = (bid - TBLOCKS) * 256 + t;
        for (int i = idx; i < NA * MUL; i += EBLOCKS * 256) {
            int a = i >> 6, c = i & 63;
            h0row[i] = Wemb[nodes[a] * MUL + c];
        }
    } else if (bid < TBLOCKS + EBLOCKS + ASCAN) {
        // ---------------- atom-graph scan ----------------
        int nglob = (bid - TBLOCKS - EBLOCKS) * 4 + (t >> 6);
        int b = nglob / Nc, nloc = nglob % Nc;
        float px = apos[nglob * 3 + 0], py = apos[nglob * 3 + 1], pz = apos[nglob * 3 + 2];
        scan_node(a_edges + (size_t)b * Ec * 2, a_disp + (size_t)b * Ec * 3,
                  apos, px, py, pz, cell + b * 9, b, nloc, Ec, nglob,
                  sdst, br_a, bs_a, cnt_a);
    } else {
        // ---------------- probe-graph scan ----------------
        int nglob = (bid - TBLOCKS - EBLOCKS - ASCAN) * 4 + (t >> 6);
        int b = nglob / Pc, nloc = nglob % Pc;
        float px = ppos[nglob * 3 + 0], py = ppos[nglob * 3 + 1], pz = ppos[nglob * 3 + 2];
        scan_node(p_edges + (size_t)b * PEc * 2, p_disp + (size_t)b * PEc * 3,
                  apos, px, py, pz, cell + b * 9, b, nloc, PEc, nglob,
                  sdst, br_p, bs_p, cnt_p);
    }
}

// ---------------------------------------------------------------------------
// Atom conv layer (row-0 only), wave per node, 4 waves/block (r11 champion).
// ---------------------------------------------------------------------------
__global__ __launch_bounds__(256) void layer_kernel(
    const float* __restrict__ hsrc,   // (n_src,64)
    float* __restrict__ outb,         // (n_out,64); base==hsrc (residual)
    const int* __restrict__ cnt,
    const float* __restrict__ brk, const int* __restrict__ bsk,
    const float2* __restrict__ wtab,  // (TBL,64) (w,dw)
    const float* __restrict__ Wl0)    // (64,64)
{
    __shared__ float tile[4][64];
    int c = threadIdx.x & 63;
    int w = threadIdx.x >> 6;
    int n = blockIdx.x * 4 + w;

    int m = min(cnt[n], CAP);
    float rvec = 0.0f; int svec = 0;
    if (c < m) { rvec = brk[(size_t)n * CAP + c]; svec = bsk[(size_t)n * CAP + c]; }
    float acc = 0.0f;
    const float scale = (float)TBL / RMAXT;
#pragma unroll 4
    for (int p = 0; p < m; ++p) {
        float rr = lane_bcast_f(rvec, p);
        int sg = __builtin_amdgcn_readlane(svec, p);
        float x = fminf(rr * scale, (float)TBL - 1.001f);
        int i0 = (int)x;
        float f = x - (float)i0;
        float2 v = wtab[(size_t)i0 * MUL + c];
        float wvv = fmaf(v.y, f, v.x);
        acc = fmaf(hsrc[(size_t)sg * MUL + c], wvv, acc);
    }
    acc *= 0.22360679774997896f;  // 1/sqrt(20)

    tile[w][c] = acc;             // same-wave LDS RAW; no barrier needed
    float u = 0.0f;
#pragma unroll
    for (int k4 = 0; k4 < 16; ++k4) {
        float4 av = *(const float4*)&tile[w][k4 * 4];
        u = fmaf(av.x, Wl0[(k4 * 4 + 0) * 64 + c], u);
        u = fmaf(av.y, Wl0[(k4 * 4 + 1) * 64 + c], u);
        u = fmaf(av.z, Wl0[(k4 * 4 + 2) * 64 + c], u);
        u = fmaf(av.w, Wl0[(k4 * 4 + 3) * 64 + c], u);
    }
    outb[(size_t)n * MUL + c] = hsrc[(size_t)n * MUL + c] + silu_f(u);
}

// ---------------------------------------------------------------------------
// Fused probe pipeline (r11 champion form): 3 probe conv layers + readout.
// ---------------------------------------------------------------------------
__global__ __launch_bounds__(256) void probe3_kernel(
    const float* __restrict__ rep0, const float* __restrict__ rep1,
    const float* __restrict__ rep2,
    const int* __restrict__ cnt,
    const float* __restrict__ brk, const int* __restrict__ bsk,
    const float2* __restrict__ wtab,  // probe tables base (3 x TBL x 64)
    const float* __restrict__ pWl,    // (3,3,64,64); l0 slice per t
    const float* __restrict__ Wout,   // (64)
    float* __restrict__ out)          // (NP)
{
    __shared__ float tile[4][64];
    int c = threadIdx.x & 63;
    int w = threadIdx.x >> 6;
    int n = blockIdx.x * 4 + w;

    int m = min(cnt[n], CAP);
    float rvec = 0.0f; int svec = 0;
    if (c < m) { rvec = brk[(size_t)n * CAP + c]; svec = bsk[(size_t)n * CAP + c]; }
    float acc0 = 0.0f, acc1 = 0.0f, acc2 = 0.0f;
    const float scale = (float)TBL / RMAXT;
    const float2* wt0 = wtab;
    const float2* wt1 = wtab + (size_t)TBL * MUL;
    const float2* wt2 = wtab + (size_t)2 * TBL * MUL;
#pragma unroll 2
    for (int p = 0; p < m; ++p) {
        float rr = lane_bcast_f(rvec, p);
        int sg = __builtin_amdgcn_readlane(svec, p);
        float x = fminf(rr * scale, (float)TBL - 1.001f);
        int i0 = (int)x;
        float f = x - (float)i0;
        size_t rowo = (size_t)i0 * MUL + c;
        float2 v0 = wt0[rowo], v1 = wt1[rowo], v2 = wt2[rowo];
        float wv0 = fmaf(v0.y, f, v0.x);
        float wv1 = fmaf(v1.y, f, v1.x);
        float wv2 = fmaf(v2.y, f, v2.x);
        size_t so = (size_t)sg * MUL + c;
        acc0 = fmaf(rep0[so], wv0, acc0);
        acc1 = fmaf(rep1[so], wv1, acc1);
        acc2 = fmaf(rep2[so], wv2, acc2);
    }
    const float isk = 0.22360679774997896f;  // 1/sqrt(20)
    float res = 0.0f;
    float accs[3] = {acc0, acc1, acc2};
#pragma unroll
    for (int tt = 0; tt < 3; ++tt) {
        tile[w][c] = accs[tt] * isk;          // same-wave LDS RAW
        const float* W = pWl + (size_t)tt * 3 * MUL * MUL;  // l0 slice
        float u = 0.0f;
#pragma unroll
        for (int k4 = 0; k4 < 16; ++k4) {
            float4 av = *(const float4*)&tile[w][k4 * 4];
            u = fmaf(av.x, W[(k4 * 4 + 0) * 64 + c], u);
            u = fmaf(av.y, W[(k4 * 4 + 1) * 64 + c], u);
            u = fmaf(av.z, W[(k4 * 4 + 2) * 64 + c], u);
            u = fmaf(av.w, W[(k4 * 4 + 3) * 64 + c], u);
        }
        res += silu_f(u);
    }

    float v = res * Wout[c];
#pragma unroll
    for (int o = 32; o > 0; o >>= 1) v += __shfl_down(v, o, 64);
    if (c == 0) out[n] = v;
}

// ---------------------------------------------------------------------------
extern "C" void kernel_launch(void* const* d_in, const int* in_sizes, int n_in,
                              void* d_out, int out_size, void* d_ws, size_t ws_size,
                              hipStream_t stream)
{
    const float* atom_xyz  = (const float*)d_in[0];
    const float* a_disp    = (const float*)d_in[1];
    const float* cell      = (const float*)d_in[2];
    const float* probe_xyz = (const float*)d_in[3];
    const float* p_disp    = (const float*)d_in[4];
    const float* W_embed   = (const float*)d_in[5];
    const float* Wr1       = (const float*)d_in[6];
    const float* br1       = (const float*)d_in[7];
    const float* Wr2       = (const float*)d_in[8];
    const float* br2       = (const float*)d_in[9];
    const float* Wl        = (const float*)d_in[10];
    const float* pWr1      = (const float*)d_in[12];
    const float* pbr1      = (const float*)d_in[13];
    const float* pWr2      = (const float*)d_in[14];
    const float* pbr2      = (const float*)d_in[15];
    const float* pWl       = (const float*)d_in[16];
    const float* W_out     = (const float*)d_in[18];
    const int*   atom_edges  = (const int*)d_in[19];
    const int*   probe_edges = (const int*)d_in[20];
    const int*   nodes       = (const int*)d_in[21];
    float* out = (float*)d_out;

    char* w = (char*)d_ws;
    auto alloc = [&](size_t bytes) -> void* {
        void* r = (void*)w;
        w += (bytes + 255) & ~(size_t)255;
        return r;
    };
    int*   cnt_a  = (int*)alloc((size_t)NA * 4);
    int*   cnt_p  = (int*)alloc((size_t)NP * 4);
    float* br_a   = (float*)alloc((size_t)NA * CAP * 4);
    int*   bs_a   = (int*)alloc((size_t)NA * CAP * 4);
    float* br_p   = (float*)alloc((size_t)NP * CAP * 4);
    int*   bs_p   = (int*)alloc((size_t)NP * CAP * 4);
    float* h0row  = (float*)alloc((size_t)NA * MUL * 4);
    float* rep0   = (float*)alloc((size_t)NA * MUL * 4);
    float* rep1   = (float*)alloc((size_t)NA * MUL * 4);
    float* rep2   = (float*)alloc((size_t)NA * MUL * 4);
    float2* wtab  = (float2*)alloc((size_t)6 * TBL * MUL * 8);

    // 1) mega-front: tables + embedding + BOTH graphs' buckets (scan, no atomics)
    megafront_kernel<<<TBLOCKS + EBLOCKS + ASCAN + PSCAN, 256, 0, stream>>>(
        Wr1, pWr1, br1, pbr1, Wr2, pWr2, br2, pbr2,
        nodes, W_embed, atom_xyz, probe_xyz, atom_edges, probe_edges,
        a_disp, p_disp, cell, h0row,
        cnt_a, br_a, bs_a, cnt_p, br_p, bs_p, wtab);

    // 2-4) atom layers (sequential residual chain)
    const float* hprev = h0row;
    float* reps[3] = {rep0, rep1, rep2};
    for (int t = 0; t < Tc; ++t) {
        layer_kernel<<<NA / 4, 256, 0, stream>>>(
            hprev, reps[t], cnt_a, br_a, bs_a,
            wtab + (size_t)t * TBL * MUL,
            Wl + (size_t)t * 3 * MUL * MUL);
        hprev = reps[t];
    }

    // 5) fused probe layers + readout
    probe3_kernel<<<NP / 4, 256, 0, stream>>>(
        rep0, rep1, rep2, cnt_p, br_p, bs_p,
        wtab + (size_t)3 * TBL * MUL, pWl, W_out, out);
}

// Round 16
// 77.296 us; speedup vs baseline: 1.8188x; 1.8188x over previous
//
#include <hip/hip_runtime.h>
#include <math.h>

#define Bc 4
#define Nc 512
#define Pc 1024
#define Kc 20
#define MUL 64
#define NBc 20
#define HID 100
#define Tc 3
#define CUTc 4.0f
#define Ec (Nc * Kc)        /* 10240 */
#define PEc (Pc * Kc)       /* 20480 */
#define NA (Bc * Nc)        /* 2048 */
#define NP (Bc * Pc)        /* 4096 */
#define ET (Bc * Ec)        /* 40960 */
#define PET (Bc * PEc)      /* 81920 */
#define TBL 1024            /* w-table points over r in [0, RMAXT]; r13/r14: absmax-insensitive */
#define RMAXT 5.25f         /* rbf(r) dead beyond ~5 (centers end 4.0, sigma 0.2) */
#define CAP 64              /* bucket capacity per dst (max degree ~38 expected) */
#define TROWS 8             /* table rows per block in front_kernel */
#define TBLOCKS (6 * TBL / TROWS)  /* 768 */
#define ZBLOCKS 8
#define EBLOCKS 32

__device__ __forceinline__ float silu_f(float x) { return x / (1.0f + __expf(-x)); }
__device__ __forceinline__ float lane_bcast_f(float v, int l) {
    return __int_as_float(__builtin_amdgcn_readlane(__float_as_int(v), l));
}

// ---------------------------------------------------------------------------
// Front kernel — all dep-free work at FULL grid width (lessons: r8/r13/r15
// never narrow the grid or add scan work when fusing; r10 never grid.sync):
//   blocks [0,768):    w-table, TROWS=8 rows/block, hidden tile in LDS
//   blocks [768,776):  zero cnt arrays (runtime fill kernel costs 41us)
//   blocks [776,808):  embedding row 0
// ---------------------------------------------------------------------------
__global__ __launch_bounds__(256) void front_kernel(
    const float* __restrict__ Wr1, const float* __restrict__ pWr1,
    const float* __restrict__ br1, const float* __restrict__ pbr1,
    const float* __restrict__ Wr2, const float* __restrict__ pWr2,
    const float* __restrict__ br2, const float* __restrict__ pbr2,
    const int* __restrict__ nodes, const float* __restrict__ Wemb,
    int* __restrict__ cnt_both, float* __restrict__ h0row,
    float* __restrict__ wtab)        // (6*TBL, 64)
{
    __shared__ float Hs[TROWS * HID];   // 3.2 KB
    int bid = blockIdx.x;
    int t = threadIdx.x;

    if (bid < TBLOCKS) {
        int grow0 = bid * TROWS;          // global table row base (same ly for all)
        int ly = grow0 / TBL;
        int t3 = (ly < 3) ? ly : ly - 3;
        const float* w1 = ((ly < 3) ? Wr1 : pWr1) + (size_t)t3 * NBc * HID;
        const float* b1 = ((ly < 3) ? br1 : pbr1) + (size_t)t3 * HID;
        const float* w2 = ((ly < 3) ? Wr2 : pWr2) + (size_t)t3 * HID * MUL;
        const float* b2 = ((ly < 3) ? br2 : pbr2) + (size_t)t3 * MUL;
        const float step = CUTc / (NBc - 1);
        const float inv_sigma = (float)NBc / CUTc;

        // phase A: hidden tile (800 entries; ~3/thread)
        for (int id = t; id < TROWS * HID; id += 256) {
            int il = id / HID, j = id - il * HID;
            float r = (float)(grow0 % TBL + il) * (RMAXT / (float)TBL);
            float s = b1[j];
#pragma unroll
            for (int k = 0; k < NBc; ++k) {
                float tt = (r - k * step) * inv_sigma;
                s = fmaf(__expf(-tt * tt), w1[k * HID + j], s);
            }
            Hs[id] = silu_f(s);
        }
        __syncthreads();

        // phase B: wave covers one row -> LDS broadcast reads + L1 W2 rows
        int il0 = t >> 6, c = t & 63;
        for (int il = il0; il < TROWS; il += 4) {
            float acc = b2[c];
#pragma unroll 4
            for (int j = 0; j < HID; ++j)
                acc = fmaf(Hs[il * HID + j], w2[(size_t)j * MUL + c], acc);
            wtab[(size_t)(grow0 + il) * MUL + c] = acc;
        }
    } else if (bid < TBLOCKS + ZBLOCKS) {
        int idx = (bid - TBLOCKS) * 256 + t;
        for (int i = idx; i < NA + NP; i += ZBLOCKS * 256) cnt_both[i] = 0;
    } else {
        int idx = (bid - TBLOCKS - ZBLOCKS) * 256 + t;
        for (int i = idx; i < NA * MUL; i += EBLOCKS * 256) {
            int a = i >> 6, c = i & 63;
            h0row[i] = Wemb[nodes[a] * MUL + c];
        }
    }
}

// ---------------------------------------------------------------------------
// Geometry + bucket fill (both graphs, one launch). Fixed CAP=64 slots/dst.
// ---------------------------------------------------------------------------
__global__ void geom_kernel(const float* __restrict__ apos,
                            const float* __restrict__ ppos,
                            const int* __restrict__ a_edges,
                            const int* __restrict__ p_edges,
                            const float* __restrict__ a_disp,
                            const float* __restrict__ p_disp,
                            const float* __restrict__ cell,
                            int* __restrict__ cnt_a, int* __restrict__ cnt_p,
                            float* __restrict__ br_a, int* __restrict__ bs_a,
                            float* __restrict__ br_p, int* __restrict__ bs_p)
{
    int e = blockIdx.x * 256 + threadIdx.x;
    if (e >= ET + PET) return;
    const int* edges; const float* displ; const float* pdst;
    int* cnt; float* brout; int* bsout;
    int el, Eper, dst_stride;
    if (e < ET) {
        el = e; edges = a_edges; displ = a_disp; pdst = apos;
        Eper = Ec; dst_stride = Nc; cnt = cnt_a; brout = br_a; bsout = bs_a;
    } else {
        el = e - ET; edges = p_edges; displ = p_disp; pdst = ppos;
        Eper = PEc; dst_stride = Pc; cnt = cnt_p; brout = br_p; bsout = bs_p;
    }
    int b = el / Eper;
    int sg = edges[el * 2 + 0] + b * Nc;
    int dg = edges[el * 2 + 1] + b * dst_stride;
    const float* C = cell + b * 9;
    float d0 = displ[el * 3 + 0], d1 = displ[el * 3 + 1], d2 = displ[el * 3 + 2];
    float dx = d0 * C[0] + d1 * C[3] + d2 * C[6];
    float dy = d0 * C[1] + d1 * C[4] + d2 * C[7];
    float dz = d0 * C[2] + d1 * C[5] + d2 * C[8];
    float vx = pdst[dg * 3 + 0] - (apos[sg * 3 + 0] + dx);
    float vy = pdst[dg * 3 + 1] - (apos[sg * 3 + 1] + dy);
    float vz = pdst[dg * 3 + 2] - (apos[sg * 3 + 2] + dz);
    float r = sqrtf(vx * vx + vy * vy + vz * vz);
    int pos = atomicAdd(&cnt[dg], 1);
    if (pos < CAP) {
        brout[(size_t)dg * CAP + pos] = r;
        bsout[(size_t)dg * CAP + pos] = sg;
    }
}

// ---------------------------------------------------------------------------
// Atom conv layer (row-0 only), wave per node, 4 waves/block. Bucket row is
// exactly one wave-wide chunk: single lane-load + readlane broadcast loop.
// ---------------------------------------------------------------------------
__global__ __launch_bounds__(256) void layer_kernel(
    const float* __restrict__ hsrc,   // (n_src,64)
    float* __restrict__ outb,         // (n_out,64); base==hsrc (residual)
    const int* __restrict__ cnt,
    const float* __restrict__ brk, const int* __restrict__ bsk,
    const float* __restrict__ wtab,
    const float* __restrict__ Wl0)    // (64,64)
{
    __shared__ float tile[4][64];
    int c = threadIdx.x & 63;
    int w = threadIdx.x >> 6;
    int n = blockIdx.x * 4 + w;

    int m = min(cnt[n], CAP);
    float rvec = 0.0f; int svec = 0;
    if (c < m) { rvec = brk[(size_t)n * CAP + c]; svec = bsk[(size_t)n * CAP + c]; }
    float acc = 0.0f;
    const float scale = (float)TBL / RMAXT;
#pragma unroll 4
    for (int p = 0; p < m; ++p) {
        float rr = lane_bcast_f(rvec, p);
        int sg = __builtin_amdgcn_readlane(svec, p);
        float x = fminf(rr * scale, (float)TBL - 1.001f);
        int i0 = (int)x;
        float f = x - (float)i0;
        const float* tp = wtab + (size_t)i0 * MUL;
        float w0 = tp[c];
        float w1 = tp[MUL + c];
        float wv = fmaf(w1 - w0, f, w0);
        acc = fmaf(hsrc[(size_t)sg * MUL + c], wv, acc);
    }
    acc *= 0.22360679774997896f;  // 1/sqrt(20)

    tile[w][c] = acc;             // same-wave LDS RAW; no barrier needed
    float u = 0.0f;
#pragma unroll
    for (int k4 = 0; k4 < 16; ++k4) {
        float4 av = *(const float4*)&tile[w][k4 * 4];
        u = fmaf(av.x, Wl0[(k4 * 4 + 0) * 64 + c], u);
        u = fmaf(av.y, Wl0[(k4 * 4 + 1) * 64 + c], u);
        u = fmaf(av.z, Wl0[(k4 * 4 + 2) * 64 + c], u);
        u = fmaf(av.w, Wl0[(k4 * 4 + 3) * 64 + c], u);
    }
    outb[(size_t)n * MUL + c] = hsrc[(size_t)n * MUL + c] + silu_f(u);
}

// ---------------------------------------------------------------------------
// Fused probe pipeline: all 3 probe conv layers + readout in one kernel.
// ---------------------------------------------------------------------------
__global__ __launch_bounds__(256) void probe3_kernel(
    const float* __restrict__ rep0, const float* __restrict__ rep1,
    const float* __restrict__ rep2,
    const int* __restrict__ cnt,
    const float* __restrict__ brk, const int* __restrict__ bsk,
    const float* __restrict__ wtab,  // probe tables base (3 x TBL x 64)
    const float* __restrict__ pWl,   // (3,3,64,64); l0 slice per t
    const float* __restrict__ Wout,  // (64)
    float* __restrict__ out)         // (NP)
{
    __shared__ float tile[4][64];
    int c = threadIdx.x & 63;
    int w = threadIdx.x >> 6;
    int n = blockIdx.x * 4 + w;

    int m = min(cnt[n], CAP);
    float rvec = 0.0f; int svec = 0;
    if (c < m) { rvec = brk[(size_t)n * CAP + c]; svec = bsk[(size_t)n * CAP + c]; }
    float acc0 = 0.0f, acc1 = 0.0f, acc2 = 0.0f;
    const float scale = (float)TBL / RMAXT;
    const float* wt0 = wtab;
    const float* wt1 = wtab + (size_t)TBL * MUL;
    const float* wt2 = wtab + (size_t)2 * TBL * MUL;
#pragma unroll 2
    for (int p = 0; p < m; ++p) {
        float rr = lane_bcast_f(rvec, p);
        int sg = __builtin_amdgcn_readlane(svec, p);
        float x = fminf(rr * scale, (float)TBL - 1.001f);
        int i0 = (int)x;
        float f = x - (float)i0;
        size_t rowo = (size_t)i0 * MUL + c;
        float wv0 = fmaf(wt0[rowo + MUL] - wt0[rowo], f, wt0[rowo]);
        float wv1 = fmaf(wt1[rowo + MUL] - wt1[rowo], f, wt1[rowo]);
        float wv2 = fmaf(wt2[rowo + MUL] - wt2[rowo], f, wt2[rowo]);
        size_t so = (size_t)sg * MUL + c;
        acc0 = fmaf(rep0[so], wv0, acc0);
        acc1 = fmaf(rep1[so], wv1, acc1);
        acc2 = fmaf(rep2[so], wv2, acc2);
    }
    const float isk = 0.22360679774997896f;  // 1/sqrt(20)
    float res = 0.0f;
    float accs[3] = {acc0, acc1, acc2};
#pragma unroll
    for (int t = 0; t < 3; ++t) {
        tile[w][c] = accs[t] * isk;          // same-wave LDS RAW
        const float* W = pWl + (size_t)t * 3 * MUL * MUL;  // l0 slice
        float u = 0.0f;
#pragma unroll
        for (int k4 = 0; k4 < 16; ++k4) {
            float4 av = *(const float4*)&tile[w][k4 * 4];
            u = fmaf(av.x, W[(k4 * 4 + 0) * 64 + c], u);
            u = fmaf(av.y, W[(k4 * 4 + 1) * 64 + c], u);
            u = fmaf(av.z, W[(k4 * 4 + 2) * 64 + c], u);
            u = fmaf(av.w, W[(k4 * 4 + 3) * 64 + c], u);
        }
        res += silu_f(u);
    }

    float v = res * Wout[c];
#pragma unroll
    for (int o = 32; o > 0; o >>= 1) v += __shfl_down(v, o, 64);
    if (c == 0) out[n] = v;
}

// ---------------------------------------------------------------------------
extern "C" void kernel_launch(void* const* d_in, const int* in_sizes, int n_in,
                              void* d_out, int out_size, void* d_ws, size_t ws_size,
                              hipStream_t stream)
{
    const float* atom_xyz  = (const float*)d_in[0];
    const float* a_disp    = (const float*)d_in[1];
    const float* cell      = (const float*)d_in[2];
    const float* probe_xyz = (const float*)d_in[3];
    const float* p_disp    = (const float*)d_in[4];
    const float* W_embed   = (const float*)d_in[5];
    const float* Wr1       = (const float*)d_in[6];
    const float* br1       = (const float*)d_in[7];
    const float* Wr2       = (const float*)d_in[8];
    const float* br2       = (const float*)d_in[9];
    const float* Wl        = (const float*)d_in[10];
    const float* pWr1      = (const float*)d_in[12];
    const float* pbr1      = (const float*)d_in[13];
    const float* pWr2      = (const float*)d_in[14];
    const float* pbr2      = (const float*)d_in[15];
    const float* pWl       = (const float*)d_in[16];
    const float* W_out     = (const float*)d_in[18];
    const int*   atom_edges  = (const int*)d_in[19];
    const int*   probe_edges = (const int*)d_in[20];
    const int*   nodes       = (const int*)d_in[21];
    float* out = (float*)d_out;

    char* w = (char*)d_ws;
    auto alloc = [&](size_t bytes) -> void* {
        void* r = (void*)w;
        w += (bytes + 255) & ~(size_t)255;
        return r;
    };
    int*   cnt_both = (int*)alloc((size_t)(NA + NP) * 4);
    int*   cnt_a  = cnt_both;
    int*   cnt_p  = cnt_both + NA;
    float* br_a   = (float*)alloc((size_t)NA * CAP * 4);
    int*   bs_a   = (int*)alloc((size_t)NA * CAP * 4);
    float* br_p   = (float*)alloc((size_t)NP * CAP * 4);
    int*   bs_p   = (int*)alloc((size_t)NP * CAP * 4);
    float* h0row  = (float*)alloc((size_t)NA * MUL * 4);
    float* rep0   = (float*)alloc((size_t)NA * MUL * 4);
    float* rep1   = (float*)alloc((size_t)NA * MUL * 4);
    float* rep2   = (float*)alloc((size_t)NA * MUL * 4);
    float* wtab   = (float*)alloc((size_t)6 * TBL * MUL * 4);

    // 1) dep-free front-end: fused w-table + cnt zero + embedding
    front_kernel<<<TBLOCKS + ZBLOCKS + EBLOCKS, 256, 0, stream>>>(
        Wr1, pWr1, br1, pbr1, Wr2, pWr2, br2, pbr2,
        nodes, W_embed, cnt_both, h0row, wtab);

    // 2) geometry + bucket fill (replaces count/scan/geom chain)
    geom_kernel<<<(ET + PET + 255) / 256, 256, 0, stream>>>(
        atom_xyz, probe_xyz, atom_edges, probe_edges, a_disp, p_disp, cell,
        cnt_a, cnt_p, br_a, bs_a, br_p, bs_p);

    // 3-5) atom layers (sequential residual chain)
    const float* hprev = h0row;
    float* reps[3] = {rep0, rep1, rep2};
    for (int t = 0; t < Tc; ++t) {
        layer_kernel<<<NA / 4, 256, 0, stream>>>(
            hprev, reps[t], cnt_a, br_a, bs_a,
            wtab + (size_t)t * TBL * MUL,
            Wl + (size_t)t * 3 * MUL * MUL);
        hprev = reps[t];
    }

    // 6) fused probe layers + readout
    probe3_kernel<<<NP / 4, 256, 0, stream>>>(
        rep0, rep1, rep2, cnt_p, br_p, bs_p,
        wtab + (size_t)3 * TBL * MUL, pWl, W_out, out);
}

// Round 17
// 76.825 us; speedup vs baseline: 1.8299x; 1.0061x over previous
//
#include <hip/hip_runtime.h>
#include <math.h>

#define Bc 4
#define Nc 512
#define Pc 1024
#define Kc 20
#define MUL 64
#define NBc 20
#define HID 100
#define Tc 3
#define CUTc 4.0f
#define Ec (Nc * Kc)        /* 10240 */
#define PEc (Pc * Kc)       /* 20480 */
#define NA (Bc * Nc)        /* 2048 */
#define NP (Bc * Pc)        /* 4096 */
#define ET (Bc * Ec)        /* 40960 */
#define PET (Bc * PEc)      /* 81920 */
#define TBL 1024            /* w-table points over r in [0, RMAXT]; absmax-insensitive */
#define RMAXT 5.25f         /* rbf(r) dead beyond ~5 (centers end 4.0, sigma 0.2) */
#define CAP 64              /* bucket capacity per dst (max degree ~38 expected) */
#define TROWS 8
#define TBLOCKS (6 * TBL / TROWS)  /* 768 */
#define ZBLOCKS 8
#define EBLOCKS 32

__device__ __forceinline__ float silu_f(float x) { return x / (1.0f + __expf(-x)); }
__device__ __forceinline__ float lane_bcast_f(float v, int l) {
    return __int_as_float(__builtin_amdgcn_readlane(__float_as_int(v), l));
}

// ---------------------------------------------------------------------------
// Front kernel (r16 champion form): tables + cnt-zero + embedding, full width.
// ---------------------------------------------------------------------------
__global__ __launch_bounds__(256) void front_kernel(
    const float* __restrict__ Wr1, const float* __restrict__ pWr1,
    const float* __restrict__ br1, const float* __restrict__ pbr1,
    const float* __restrict__ Wr2, const float* __restrict__ pWr2,
    const float* __restrict__ br2, const float* __restrict__ pbr2,
    const int* __restrict__ nodes, const float* __restrict__ Wemb,
    int* __restrict__ cnt_both, float* __restrict__ h0row,
    float* __restrict__ wtab)        // (6*TBL, 64)
{
    __shared__ float Hs[TROWS * HID];   // 3.2 KB
    int bid = blockIdx.x;
    int t = threadIdx.x;

    if (bid < TBLOCKS) {
        int grow0 = bid * TROWS;
        int ly = grow0 / TBL;
        int t3 = (ly < 3) ? ly : ly - 3;
        const float* w1 = ((ly < 3) ? Wr1 : pWr1) + (size_t)t3 * NBc * HID;
        const float* b1 = ((ly < 3) ? br1 : pbr1) + (size_t)t3 * HID;
        const float* w2 = ((ly < 3) ? Wr2 : pWr2) + (size_t)t3 * HID * MUL;
        const float* b2 = ((ly < 3) ? br2 : pbr2) + (size_t)t3 * MUL;
        const float step = CUTc / (NBc - 1);
        const float inv_sigma = (float)NBc / CUTc;

        for (int id = t; id < TROWS * HID; id += 256) {
            int il = id / HID, j = id - il * HID;
            float r = (float)(grow0 % TBL + il) * (RMAXT / (float)TBL);
            float s = b1[j];
#pragma unroll
            for (int k = 0; k < NBc; ++k) {
                float tt = (r - k * step) * inv_sigma;
                s = fmaf(__expf(-tt * tt), w1[k * HID + j], s);
            }
            Hs[id] = silu_f(s);
        }
        __syncthreads();

        int il0 = t >> 6, c = t & 63;
        for (int il = il0; il < TROWS; il += 4) {
            float acc = b2[c];
#pragma unroll 4
            for (int j = 0; j < HID; ++j)
                acc = fmaf(Hs[il * HID + j], w2[(size_t)j * MUL + c], acc);
            wtab[(size_t)(grow0 + il) * MUL + c] = acc;
        }
    } else if (bid < TBLOCKS + ZBLOCKS) {
        int idx = (bid - TBLOCKS) * 256 + t;
        for (int i = idx; i < NA + NP; i += ZBLOCKS * 256) cnt_both[i] = 0;
    } else {
        int idx = (bid - TBLOCKS - ZBLOCKS) * 256 + t;
        for (int i = idx; i < NA * MUL; i += EBLOCKS * 256) {
            int a = i >> 6, c = i & 63;
            h0row[i] = Wemb[nodes[a] * MUL + c];
        }
    }
}

// ---------------------------------------------------------------------------
// Geometry + bucket fill (both graphs, one launch). Fixed CAP=64 slots/dst.
// ---------------------------------------------------------------------------
__global__ void geom_kernel(const float* __restrict__ apos,
                            const float* __restrict__ ppos,
                            const int* __restrict__ a_edges,
                            const int* __restrict__ p_edges,
                            const float* __restrict__ a_disp,
                            const float* __restrict__ p_disp,
                            const float* __restrict__ cell,
                            int* __restrict__ cnt_a, int* __restrict__ cnt_p,
                            float* __restrict__ br_a, int* __restrict__ bs_a,
                            float* __restrict__ br_p, int* __restrict__ bs_p)
{
    int e = blockIdx.x * 256 + threadIdx.x;
    if (e >= ET + PET) return;
    const int* edges; const float* displ; const float* pdst;
    int* cnt; float* brout; int* bsout;
    int el, Eper, dst_stride;
    if (e < ET) {
        el = e; edges = a_edges; displ = a_disp; pdst = apos;
        Eper = Ec; dst_stride = Nc; cnt = cnt_a; brout = br_a; bsout = bs_a;
    } else {
        el = e - ET; edges = p_edges; displ = p_disp; pdst = ppos;
        Eper = PEc; dst_stride = Pc; cnt = cnt_p; brout = br_p; bsout = bs_p;
    }
    int b = el / Eper;
    int sg = edges[el * 2 + 0] + b * Nc;
    int dg = edges[el * 2 + 1] + b * dst_stride;
    const float* C = cell + b * 9;
    float d0 = displ[el * 3 + 0], d1 = displ[el * 3 + 1], d2 = displ[el * 3 + 2];
    float dx = d0 * C[0] + d1 * C[3] + d2 * C[6];
    float dy = d0 * C[1] + d1 * C[4] + d2 * C[7];
    float dz = d0 * C[2] + d1 * C[5] + d2 * C[8];
    float vx = pdst[dg * 3 + 0] - (apos[sg * 3 + 0] + dx);
    float vy = pdst[dg * 3 + 1] - (apos[sg * 3 + 1] + dy);
    float vz = pdst[dg * 3 + 2] - (apos[sg * 3 + 2] + dz);
    float r = sqrtf(vx * vx + vy * vy + vz * vz);
    int pos = atomicAdd(&cnt[dg], 1);
    if (pos < CAP) {
        brout[(size_t)dg * CAP + pos] = r;
        bsout[(size_t)dg * CAP + pos] = sg;
    }
}

// ---------------------------------------------------------------------------
// Combined launch: blocks [0, atomBlocks) run atom conv layer t (r16 form);
// blocks [atomBlocks, atomBlocks + NP/4) run probe part `phase`:
//   gather over probe bucket with table/rep of layer `phase`, GEMV + silu,
//   accumulate resbuf; phase 2 adds the W_out dot + final store.
// Probe layer `phase` depends only on rep_phase (written by the PREVIOUS
// launch's atom part), so the parts pipeline behind the atom chain.
// ---------------------------------------------------------------------------
__global__ __launch_bounds__(256) void layer_probe_kernel(
    // atom part (ignored when atomBlocks == 0)
    const float* __restrict__ hsrc, float* __restrict__ outb,
    const int* __restrict__ cnt_a,
    const float* __restrict__ br_a, const int* __restrict__ bs_a,
    const float* __restrict__ awt, const float* __restrict__ Wl0,
    int atomBlocks,
    // probe part
    const float* __restrict__ rept,
    const int* __restrict__ cnt_p,
    const float* __restrict__ br_p, const int* __restrict__ bs_p,
    const float* __restrict__ pwt, const float* __restrict__ pWl0,
    float* __restrict__ resbuf, const float* __restrict__ Wout,
    float* __restrict__ out, int phase)
{
    __shared__ float tile[4][64];
    int c = threadIdx.x & 63;
    int w = threadIdx.x >> 6;
    const float scale = (float)TBL / RMAXT;
    const float isk = 0.22360679774997896f;  // 1/sqrt(20)

    if (blockIdx.x < (unsigned)atomBlocks) {
        // ---------------- atom conv layer ----------------
        int n = blockIdx.x * 4 + w;
        int m = min(cnt_a[n], CAP);
        float rvec = 0.0f; int svec = 0;
        if (c < m) { rvec = br_a[(size_t)n * CAP + c]; svec = bs_a[(size_t)n * CAP + c]; }
        float acc = 0.0f;
#pragma unroll 4
        for (int p = 0; p < m; ++p) {
            float rr = lane_bcast_f(rvec, p);
            int sg = __builtin_amdgcn_readlane(svec, p);
            float x = fminf(rr * scale, (float)TBL - 1.001f);
            int i0 = (int)x;
            float f = x - (float)i0;
            const float* tp = awt + (size_t)i0 * MUL;
            float w0 = tp[c];
            float w1 = tp[MUL + c];
            float wv = fmaf(w1 - w0, f, w0);
            acc = fmaf(hsrc[(size_t)sg * MUL + c], wv, acc);
        }
        tile[w][c] = acc * isk;       // same-wave LDS RAW; no barrier needed
        float u = 0.0f;
#pragma unroll
        for (int k4 = 0; k4 < 16; ++k4) {
            float4 av = *(const float4*)&tile[w][k4 * 4];
            u = fmaf(av.x, Wl0[(k4 * 4 + 0) * 64 + c], u);
            u = fmaf(av.y, Wl0[(k4 * 4 + 1) * 64 + c], u);
            u = fmaf(av.z, Wl0[(k4 * 4 + 2) * 64 + c], u);
            u = fmaf(av.w, Wl0[(k4 * 4 + 3) * 64 + c], u);
        }
        outb[(size_t)n * MUL + c] = hsrc[(size_t)n * MUL + c] + silu_f(u);
    } else {
        // ---------------- probe part `phase` ----------------
        int n = (blockIdx.x - atomBlocks) * 4 + w;
        int m = min(cnt_p[n], CAP);
        float rvec = 0.0f; int svec = 0;
        if (c < m) { rvec = br_p[(size_t)n * CAP + c]; svec = bs_p[(size_t)n * CAP + c]; }
        float acc = 0.0f;
#pragma unroll 4
        for (int p = 0; p < m; ++p) {
            float rr = lane_bcast_f(rvec, p);
            int sg = __builtin_amdgcn_readlane(svec, p);
            float x = fminf(rr * scale, (float)TBL - 1.001f);
            int i0 = (int)x;
            float f = x - (float)i0;
            const float* tp = pwt + (size_t)i0 * MUL;
            float w0 = tp[c];
            float w1 = tp[MUL + c];
            float wv = fmaf(w1 - w0, f, w0);
            acc = fmaf(rept[(size_t)sg * MUL + c], wv, acc);
        }
        tile[w][c] = acc * isk;       // same-wave LDS RAW
        float u = 0.0f;
#pragma unroll
        for (int k4 = 0; k4 < 16; ++k4) {
            float4 av = *(const float4*)&tile[w][k4 * 4];
            u = fmaf(av.x, pWl0[(k4 * 4 + 0) * 64 + c], u);
            u = fmaf(av.y, pWl0[(k4 * 4 + 1) * 64 + c], u);
            u = fmaf(av.z, pWl0[(k4 * 4 + 2) * 64 + c], u);
            u = fmaf(av.w, pWl0[(k4 * 4 + 3) * 64 + c], u);
        }
        float s = silu_f(u);
        size_t idx = (size_t)n * MUL + c;
        if (phase == 0) {
            resbuf[idx] = s;
        } else if (phase == 1) {
            resbuf[idx] += s;
        } else {
            float res = resbuf[idx] + s;
            float v = res * Wout[c];
#pragma unroll
            for (int o = 32; o > 0; o >>= 1) v += __shfl_down(v, o, 64);
            if (c == 0) out[n] = v;
        }
    }
}

// ---------------------------------------------------------------------------
extern "C" void kernel_launch(void* const* d_in, const int* in_sizes, int n_in,
                              void* d_out, int out_size, void* d_ws, size_t ws_size,
                              hipStream_t stream)
{
    const float* atom_xyz  = (const float*)d_in[0];
    const float* a_disp    = (const float*)d_in[1];
    const float* cell      = (const float*)d_in[2];
    const float* probe_xyz = (const float*)d_in[3];
    const float* p_disp    = (const float*)d_in[4];
    const float* W_embed   = (const float*)d_in[5];
    const float* Wr1       = (const float*)d_in[6];
    const float* br1       = (const float*)d_in[7];
    const float* Wr2       = (const float*)d_in[8];
    const float* br2       = (const float*)d_in[9];
    const float* Wl        = (const float*)d_in[10];
    const float* pWr1      = (const float*)d_in[12];
    const float* pbr1      = (const float*)d_in[13];
    const float* pWr2      = (const float*)d_in[14];
    const float* pbr2      = (const float*)d_in[15];
    const float* pWl       = (const float*)d_in[16];
    const float* W_out     = (const float*)d_in[18];
    const int*   atom_edges  = (const int*)d_in[19];
    const int*   probe_edges = (const int*)d_in[20];
    const int*   nodes       = (const int*)d_in[21];
    float* out = (float*)d_out;

    char* w = (char*)d_ws;
    auto alloc = [&](size_t bytes) -> void* {
        void* r = (void*)w;
        w += (bytes + 255) & ~(size_t)255;
        return r;
    };
    int*   cnt_both = (int*)alloc((size_t)(NA + NP) * 4);
    int*   cnt_a  = cnt_both;
    int*   cnt_p  = cnt_both + NA;
    float* br_a   = (float*)alloc((size_t)NA * CAP * 4);
    int*   bs_a   = (int*)alloc((size_t)NA * CAP * 4);
    float* br_p   = (float*)alloc((size_t)NP * CAP * 4);
    int*   bs_p   = (int*)alloc((size_t)NP * CAP * 4);
    float* h0row  = (float*)alloc((size_t)NA * MUL * 4);
    float* rep0   = (float*)alloc((size_t)NA * MUL * 4);
    float* rep1   = (float*)alloc((size_t)NA * MUL * 4);
    float* rep2   = (float*)alloc((size_t)NA * MUL * 4);
    float* resbuf = (float*)alloc((size_t)NP * MUL * 4);
    float* wtab   = (float*)alloc((size_t)6 * TBL * MUL * 4);
    float* pwtab  = wtab + (size_t)3 * TBL * MUL;

    const int AB = NA / 4;   // 512 atom blocks
    const int PB = NP / 4;   // 1024 probe blocks

    // 1) dep-free front-end: tables + cnt zero + embedding
    front_kernel<<<TBLOCKS + ZBLOCKS + EBLOCKS, 256, 0, stream>>>(
        Wr1, pWr1, br1, pbr1, Wr2, pWr2, br2, pbr2,
        nodes, W_embed, cnt_both, h0row, wtab);

    // 2) geometry + bucket fill
    geom_kernel<<<(ET + PET + 255) / 256, 256, 0, stream>>>(
        atom_xyz, probe_xyz, atom_edges, probe_edges, a_disp, p_disp, cell,
        cnt_a, cnt_p, br_a, bs_a, br_p, bs_p);

    // 3) atom L0 only (probe part 0 needs rep0, produced here)
    layer_probe_kernel<<<AB, 256, 0, stream>>>(
        h0row, rep0, cnt_a, br_a, bs_a, wtab, Wl,
        AB,
        nullptr, cnt_p, br_p, bs_p, nullptr, nullptr, resbuf, W_out, out, 0);

    // 4) atom L1 || probe part 0 (reads rep0)
    layer_probe_kernel<<<AB + PB, 256, 0, stream>>>(
        rep0, rep1, cnt_a, br_a, bs_a, wtab + (size_t)TBL * MUL, Wl + (size_t)3 * MUL * MUL,
        AB,
        rep0, cnt_p, br_p, bs_p, pwtab, pWl, resbuf, W_out, out, 0);

    // 5) atom L2 || probe part 1 (reads rep1)
    layer_probe_kernel<<<AB + PB, 256, 0, stream>>>(
        rep1, rep2, cnt_a, br_a, bs_a, wtab + (size_t)2 * TBL * MUL, Wl + (size_t)6 * MUL * MUL,
        AB,
        rep1, cnt_p, br_p, bs_p, pwtab + (size_t)TBL * MUL, pWl + (size_t)3 * MUL * MUL,
        resbuf, W_out, out, 1);

    // 6) probe part 2 (reads rep2) + epilogue
    layer_probe_kernel<<<PB, 256, 0, stream>>>(
        nullptr, nullptr, cnt_a, br_a, bs_a, nullptr, nullptr,
        0,
        rep2, cnt_p, br_p, bs_p, pwtab + (size_t)2 * TBL * MUL, pWl + (size_t)6 * MUL * MUL,
        resbuf, W_out, out, 2);
}